// Round 1
// baseline (687.120 us; speedup 1.0000x reference)
//
#include <hip/hip_runtime.h>

#define DIM 512
#define N_ROWS 16384
#define K_CODES 8192
#define BK 32
#define TM 128
#define TN 128
#define NG (K_CODES / TN)               // 64 code groups
#define OUT_ELEMS (N_ROWS * DIM)        // 8388608
#define MARGIN 0.01f
#define RESCAN_CHUNK 1024
#define RESCAN_NCHUNK (K_CODES / RESCAN_CHUNK)  // 8
#define NT (DIM / BK)                   // 16 K-tiles

typedef __bf16 bf16;
typedef __bf16 bf16x8 __attribute__((ext_vector_type(8)));
typedef float f32x4 __attribute__((ext_vector_type(4)));

// monotone float->uint map: min on packed == (min dist, then min idx)
__device__ __forceinline__ unsigned long long pack_di(float d, int i) {
  unsigned u = __float_as_uint(d);
  u = (u & 0x80000000u) ? ~u : (u | 0x80000000u);
  return ((unsigned long long)u << 32) | (unsigned)i;
}

// ---------------- kernel 0: fp32 -> (hi, lo) bf16 split (x) ----------------
__global__ __launch_bounds__(256) void vq_split_kernel(const float* __restrict__ src,
                                                       bf16* __restrict__ hi,
                                                       bf16* __restrict__ lo) {
  int i = (blockIdx.x * 256 + threadIdx.x) * 8;
  float4 v0 = *(const float4*)(src + i);
  float4 v1 = *(const float4*)(src + i + 4);
  float f[8] = {v0.x, v0.y, v0.z, v0.w, v1.x, v1.y, v1.z, v1.w};
  bf16x8 h, l;
  #pragma unroll
  for (int j = 0; j < 8; ++j) {
    bf16 hj = (bf16)f[j];              // RNE
    h[j] = hj;
    l[j] = (bf16)(f[j] - (float)hj);   // exact residual, then RNE
  }
  *(bf16x8*)(hi + i) = h;
  *(bf16x8*)(lo + i) = l;
}

// ---------------- kernel 1: emb split + per-code norms + counter zero ----------------
// one wave per code row: 64 lanes x 8 elems = 512
__global__ __launch_bounds__(256) void vq_split_enorm_kernel(
    const float* __restrict__ emb, bf16* __restrict__ eh, bf16* __restrict__ el,
    float* __restrict__ enorm, int* __restrict__ counter) {
  int gid  = blockIdx.x * 256 + threadIdx.x;
  if (gid == 0) *counter = 0;
  int code = gid >> 6;
  int lane = gid & 63;
  size_t off = (size_t)code * DIM + lane * 8;
  float4 v0 = *(const float4*)(emb + off);
  float4 v1 = *(const float4*)(emb + off + 4);
  float f[8] = {v0.x, v0.y, v0.z, v0.w, v1.x, v1.y, v1.z, v1.w};
  bf16x8 h, l;
  float s = 0.0f;
  #pragma unroll
  for (int j = 0; j < 8; ++j) {
    bf16 hj = (bf16)f[j];
    h[j] = hj;
    l[j] = (bf16)(f[j] - (float)hj);
    s = fmaf(f[j], f[j], s);
  }
  *(bf16x8*)(eh + off) = h;
  *(bf16x8*)(el + off) = l;
  #pragma unroll
  for (int o = 32; o > 0; o >>= 1) s += __shfl_down(s, o);
  if (lane == 0) enorm[code] = s;
}

// ---------------- async global->LDS 16B helper ----------------
__device__ __forceinline__ void gl2lds16(const bf16* g, bf16* l) {
  __builtin_amdgcn_global_load_lds((const __attribute__((address_space(1))) unsigned int*)g,
                                   (__attribute__((address_space(3))) unsigned int*)l,
                                   16, 0, 0);
}

__device__ __forceinline__ void top2_merge(float& d1, int& i1, float& d2,
                                           float od1, int oi1, float od2) {
  if (od1 < d1 || (od1 == d1 && oi1 < i1)) {
    d2 = fminf(d1, od2);
    d1 = od1; i1 = oi1;
  } else {
    d2 = fminf(d2, od1);
  }
}

// ---------------- kernel 2: 3-term split-bf16 MFMA GEMM + top-2 argmin ----------------
// sim = x_hi.e_hi + x_hi.e_lo + x_lo.e_hi ; dist = ||e||^2 - 2 sim (+||x||^2 const/row)
// LDS layout XOR-swizzled: 16B chunk c of row r lives at slot c ^ ((r>>1)&3).
// gl2lds dest is wave-uniform-base + lane*16, so the swizzle is applied on the
// GLOBAL SOURCE side (lane l fetches chunk (l&3)^((l>>3)&3) of its row); the
// fragment-read side applies the same XOR.
//
// Pipeline (T3 minimum 2-phase): double-buffered LDS; iteration t issues the
// global_load_lds for K-tile t+1 into buf[cur^1] BEFORE the ds_read+MFMA of
// buf[cur]. The vmcnt(0) implied by the single end-of-iteration __syncthreads
// then waits on loads already covered by ~48 MFMAs + 24 ds_reads of latency,
// instead of serially draining a just-issued stage (the old 1-phase structure,
// which capped MfmaUtil at ~50%).
__global__ __launch_bounds__(256, 2) void vq_argmin_mfma_kernel(
    const bf16* __restrict__ xh, const bf16* __restrict__ xl,
    const bf16* __restrict__ eh, const bf16* __restrict__ el,
    const float* __restrict__ enorm,
    float* __restrict__ cand_d1, int* __restrict__ cand_i1, float* __restrict__ cand_d2) {
  __shared__ __align__(16) bf16 Axh[2][TM * BK];   // 8 KB per buffer per matrix
  __shared__ __align__(16) bf16 Axl[2][TM * BK];
  __shared__ __align__(16) bf16 Beh[2][TN * BK];
  __shared__ __align__(16) bf16 Bel[2][TN * BK];
  __shared__ float red_d1[2][TM];
  __shared__ int   red_i1[2][TM];
  __shared__ float red_d2[2][TM];

  const int tid  = threadIdx.x;
  const int wave = tid >> 6;
  const int lane = tid & 63;
  const int bm = blockIdx.x, bn = blockIdx.y;
  const int wr = (wave >> 1) * 64;   // wave's row offset in tile
  const int wc = (wave & 1) * 64;    // wave's col offset in tile

  // staging: each wave owns one LDS tile; lane -> 16B chunk, 4 lanes/row.
  // global chunk fetched by lane l: (l&3) ^ ((l>>3)&3)  [source-side swizzle]
  const bf16* gsrc0;
  bf16* ldst0;   // buffer 0 dest (wave-uniform base)
  bf16* ldst1;   // buffer 1 dest
  {
    const int srow = lane >> 2;                               // 0..15
    const int scol = (((lane & 3) ^ ((lane >> 3) & 3)) * 8);  // swizzled chunk * 8 elems
    if (wave == 0)      { gsrc0 = xh + (size_t)(bm * TM + srow) * DIM + scol; ldst0 = &Axh[0][0]; ldst1 = &Axh[1][0]; }
    else if (wave == 1) { gsrc0 = xl + (size_t)(bm * TM + srow) * DIM + scol; ldst0 = &Axl[0][0]; ldst1 = &Axl[1][0]; }
    else if (wave == 2) { gsrc0 = eh + (size_t)(bn * TN + srow) * DIM + scol; ldst0 = &Beh[0][0]; ldst1 = &Beh[1][0]; }
    else                { gsrc0 = el + (size_t)(bn * TN + srow) * DIM + scol; ldst0 = &Bel[0][0]; ldst1 = &Bel[1][0]; }
  }

  f32x4 acc[4][4];
  #pragma unroll
  for (int i = 0; i < 4; ++i)
    #pragma unroll
    for (int j = 0; j < 4; ++j)
      acc[i][j] = (f32x4){0.f, 0.f, 0.f, 0.f};

  const int fr = lane & 15;   // fragment row/col within 16
  const int fq = lane >> 4;   // k-quad
  // read-side swizzle: slot of k-chunk fq for row (..+fr) = fq ^ ((fr>>1)&3); *8 elems
  const int sw8 = (fq ^ ((fr >> 1) & 3)) * 8;

  // prologue: stage K-tile 0 into buffer 0
  #pragma unroll
  for (int i = 0; i < 8; ++i)
    gl2lds16(gsrc0 + (size_t)i * 16 * DIM, ldst0 + i * 16 * BK);
  __syncthreads();   // vmcnt(0) drain + join: tile 0 resident

  for (int t = 0; t < NT; ++t) {
    const int cur = t & 1;
    // issue next tile's loads into the other buffer BEFORE compute;
    // safe: all reads of buf[cur^1] finished before the previous barrier.
    if (t + 1 < NT) {
      bf16* nb = cur ? ldst0 : ldst1;
      const int k1 = (t + 1) * BK;
      #pragma unroll
      for (int i = 0; i < 8; ++i)
        gl2lds16(gsrc0 + (size_t)i * 16 * DIM + k1, nb + i * 16 * BK);
    }

    const bf16* A_h = cur ? &Axh[1][0] : &Axh[0][0];
    const bf16* A_l = cur ? &Axl[1][0] : &Axl[0][0];
    const bf16* B_h = cur ? &Beh[1][0] : &Beh[0][0];
    const bf16* B_l = cur ? &Bel[1][0] : &Bel[0][0];

    bf16x8 ah[4], al[4], bh[4], bl[4];
    #pragma unroll
    for (int f = 0; f < 4; ++f) {
      ah[f] = *(const bf16x8*)&A_h[(wr + f * 16 + fr) * BK + sw8];
      al[f] = *(const bf16x8*)&A_l[(wr + f * 16 + fr) * BK + sw8];
      bh[f] = *(const bf16x8*)&B_h[(wc + f * 16 + fr) * BK + sw8];
      bl[f] = *(const bf16x8*)&B_l[(wc + f * 16 + fr) * BK + sw8];
    }
    #pragma unroll
    for (int mf = 0; mf < 4; ++mf)
      #pragma unroll
      for (int nf = 0; nf < 4; ++nf) {
        acc[mf][nf] = __builtin_amdgcn_mfma_f32_16x16x32_bf16(ah[mf], bh[nf], acc[mf][nf], 0, 0, 0);
        acc[mf][nf] = __builtin_amdgcn_mfma_f32_16x16x32_bf16(ah[mf], bl[nf], acc[mf][nf], 0, 0, 0);
        acc[mf][nf] = __builtin_amdgcn_mfma_f32_16x16x32_bf16(al[mf], bh[nf], acc[mf][nf], 0, 0, 0);
      }
    __syncthreads();   // drains next-tile loads (covered by MFMA) + joins waves
  }

  // ---- epilogue: distances + per-row top-2 over this block's 128 cols ----
  float en[4];
  #pragma unroll
  for (int nf = 0; nf < 4; ++nf)
    en[nf] = enorm[bn * TN + wc + nf * 16 + fr];

  #pragma unroll
  for (int mf = 0; mf < 4; ++mf) {
    #pragma unroll
    for (int reg = 0; reg < 4; ++reg) {
      float d1 = 3.4e38f, d2 = 3.4e38f;
      int i1 = 0;
      #pragma unroll
      for (int nf = 0; nf < 4; ++nf) {   // ascending col keeps lowest idx on ties
        float d = en[nf] - 2.0f * acc[mf][nf][reg];
        int ci = bn * TN + wc + nf * 16 + fr;
        if (d < d1) { d2 = d1; d1 = d; i1 = ci; }
        else if (d < d2) { d2 = d; }
      }
      // butterfly over the 16 lanes (same fq) holding this row's 64 cols
      #pragma unroll
      for (int m = 1; m <= 8; m <<= 1) {
        float od1 = __shfl_xor(d1, m, 16);
        int   oi1 = __shfl_xor(i1, m, 16);
        float od2 = __shfl_xor(d2, m, 16);
        top2_merge(d1, i1, d2, od1, oi1, od2);
      }
      if (fr == 0) {
        int row = wr + mf * 16 + fq * 4 + reg;
        red_d1[wave & 1][row] = d1;
        red_i1[wave & 1][row] = i1;
        red_d2[wave & 1][row] = d2;
      }
    }
  }
  __syncthreads();
  if (tid < TM) {
    float d1 = red_d1[0][tid]; int i1 = red_i1[0][tid]; float d2 = red_d2[0][tid];
    top2_merge(d1, i1, d2, red_d1[1][tid], red_i1[1][tid], red_d2[1][tid]);
    size_t o = (size_t)bn * N_ROWS + (size_t)bm * TM + tid;
    cand_d1[o] = d1; cand_i1[o] = i1; cand_d2[o] = d2;
  }
}

// ---------------- kernel 3: merge 64 groups -> idx, flag + compacted work list ----------------
__global__ __launch_bounds__(256) void vq_merge2_kernel(
    const float* __restrict__ cd1, const int* __restrict__ ci1, const float* __restrict__ cd2,
    int* __restrict__ idx, int* __restrict__ flag,
    int* __restrict__ counter, int* __restrict__ flagged,
    unsigned long long* __restrict__ packed,
    float* __restrict__ loss_slot) {
  int r = blockIdx.x * 256 + threadIdx.x;
  if (r == 0) *loss_slot = 0.0f;
  float d1 = 3.4e38f, d2 = 3.4e38f;
  int i1 = 0;
  for (int g = 0; g < NG; ++g) {   // ascending g = ascending col blocks
    size_t o = (size_t)g * N_ROWS + r;
    top2_merge(d1, i1, d2, cd1[o], ci1[o], cd2[o]);
  }
  idx[r] = i1;
  int f = (d2 - d1 < MARGIN) ? 1 : 0;
  flag[r] = f;
  if (f) {
    packed[r] = 0xFFFFFFFFFFFFFFFFULL;
    int slot = atomicAdd(counter, 1);
    flagged[slot] = r;
  }
}

// ---------------- kernel 4: exact fp32 rescan, parallel work-queue ----------------
__global__ __launch_bounds__(256) void vq_rescan_kernel(
    const float* __restrict__ x, const float* __restrict__ emb,
    const float* __restrict__ enorm,
    const int* __restrict__ counter, const int* __restrict__ flagged,
    unsigned long long* __restrict__ packed) {
  __shared__ float4 xs[DIM / 4];
  __shared__ float rd[256];
  __shared__ int   ri[256];
  const int t = threadIdx.x;
  const int nitems = counter[0] * RESCAN_NCHUNK;
  for (int item = blockIdx.x; item < nitems; item += gridDim.x) {
    const int r     = flagged[item / RESCAN_NCHUNK];
    const int c0    = (item % RESCAN_NCHUNK) * RESCAN_CHUNK;
    __syncthreads();   // protect xs from previous iteration's readers
    if (t < 128) xs[t] = ((const float4*)(x + (size_t)r * DIM))[t];
    __syncthreads();
    float bd = 3.4e38f; int bi = 0;
    #pragma unroll
    for (int cc = 0; cc < RESCAN_CHUNK / 256; ++cc) {
      int c = c0 + cc * 256 + t;
      const float4* e4 = (const float4*)(emb + (size_t)c * DIM);
      float s0 = 0.f, s1 = 0.f, s2 = 0.f, s3 = 0.f;
      #pragma unroll 4
      for (int k = 0; k < DIM / 4; ++k) {
        float4 xv = xs[k]; float4 ev = e4[k];
        s0 = fmaf(xv.x, ev.x, s0); s1 = fmaf(xv.y, ev.y, s1);
        s2 = fmaf(xv.z, ev.z, s2); s3 = fmaf(xv.w, ev.w, s3);
      }
      float d = enorm[c] - 2.0f * ((s0 + s1) + (s2 + s3));
      if (d < bd || (d == bd && c < bi)) { bd = d; bi = c; }
    }
    rd[t] = bd; ri[t] = bi;
    __syncthreads();
    for (int s = 128; s > 0; s >>= 1) {
      if (t < s) {
        if (rd[t + s] < rd[t] || (rd[t + s] == rd[t] && ri[t + s] < ri[t])) {
          rd[t] = rd[t + s]; ri[t] = ri[t + s];
        }
      }
      __syncthreads();
    }
    if (t == 0) atomicMin(&packed[r], pack_di(rd[0], ri[0]));
  }
}

// ---------------- kernel 5: gather + outputs + loss ----------------
__global__ __launch_bounds__(256) void vq_gather_kernel(
    const float* __restrict__ x, const float* __restrict__ emb,
    const int* __restrict__ idx, const int* __restrict__ flag,
    const unsigned long long* __restrict__ packed,
    float* __restrict__ out, float* __restrict__ quant,
    float* __restrict__ loss_slot) {
  __shared__ float wsum[4];
  const int wave = threadIdx.x >> 6;
  const int lane = threadIdx.x & 63;
  const int row  = blockIdx.x * 4 + wave;
  const int code = flag[row] ? (int)(packed[row] & 0xFFFFFFFFu) : idx[row];
  const float4* xp = (const float4*)(x   + (size_t)row  * DIM + lane * 8);
  const float4* ep = (const float4*)(emb + (size_t)code * DIM + lane * 8);
  float s = 0.0f;
  #pragma unroll
  for (int t = 0; t < 2; ++t) {
    float4 xv = xp[t];
    float4 ev = ep[t];
    float dx = ev.x - xv.x, dy = ev.y - xv.y, dz = ev.z - xv.z, dw = ev.w - xv.w;
    s += dx * dx + dy * dy + dz * dz + dw * dw;
    ((float4*)(out   + (size_t)row * DIM + lane * 8))[t] = ev;  // out == quantized (straight-through)
    ((float4*)(quant + (size_t)row * DIM + lane * 8))[t] = ev;
  }
  #pragma unroll
  for (int off = 32; off > 0; off >>= 1) s += __shfl_down(s, off);
  if (lane == 0) wsum[wave] = s;
  __syncthreads();
  if (threadIdx.x == 0) {
    float tot = wsum[0] + wsum[1] + wsum[2] + wsum[3];
    atomicAdd(loss_slot, tot * (1.25f / (float)OUT_ELEMS));
  }
}

extern "C" void kernel_launch(void* const* d_in, const int* in_sizes, int n_in,
                              void* d_out, int out_size, void* d_ws, size_t ws_size,
                              hipStream_t stream) {
  const float* x   = (const float*)d_in[0];   // [16384, 512]
  const float* emb = (const float*)d_in[1];   // [8192, 512]
  float* out   = (float*)d_out;
  float* quant = out + OUT_ELEMS;
  float* loss  = out + 2 * OUT_ELEMS;

  char* ws = (char*)d_ws;
  bf16*  xh     = (bf16*)(ws);                          // 16.78 MB
  bf16*  xl     = (bf16*)(ws + 16777216);               // 16.78 MB
  bf16*  eh     = (bf16*)(ws + 33554432);               //  8.39 MB
  bf16*  el     = (bf16*)(ws + 41943040);               //  8.39 MB
  float* enorm  = (float*)(ws + 50331648);              // 32 KB
  float* cd1    = (float*)(ws + 50364416);              // 4 MB
  int*   ci1    = (int*)  (ws + 54558720);              // 4 MB
  float* cd2    = (float*)(ws + 58753024);              // 4 MB
  int*   idx    = (int*)  (ws + 62947328);              // 64 KB
  int*   flag   = (int*)  (ws + 63012864);              // 64 KB
  int*   counter= (int*)  (ws + 63078400);              // 4 B (+pad)
  int*   flagged= (int*)  (ws + 63078656);              // 64 KB
  unsigned long long* packed = (unsigned long long*)(ws + 63144192); // 128 KB

  vq_split_kernel<<<OUT_ELEMS / (8 * 256), 256, 0, stream>>>(x, xh, xl);
  vq_split_enorm_kernel<<<K_CODES * 64 / 256, 256, 0, stream>>>(emb, eh, el, enorm, counter);
  vq_argmin_mfma_kernel<<<dim3(N_ROWS / TM, K_CODES / TN), 256, 0, stream>>>(
      xh, xl, eh, el, enorm, cd1, ci1, cd2);
  vq_merge2_kernel<<<N_ROWS / 256, 256, 0, stream>>>(
      cd1, ci1, cd2, idx, flag, counter, flagged, packed, loss);
  vq_rescan_kernel<<<2048, 256, 0, stream>>>(x, emb, enorm, counter, flagged, packed);
  vq_gather_kernel<<<N_ROWS / 4, 256, 0, stream>>>(x, emb, idx, flag, packed, out, quant, loss);
}

// Round 2
// 583.622 us; speedup vs baseline: 1.1773x; 1.1773x over previous
//
#include <hip/hip_runtime.h>

#define DIM 512
#define N_ROWS 16384
#define K_CODES 8192
#define BK 64
#define TM 128
#define TN 128
#define NG (K_CODES / TN)               // 64 code groups
#define OUT_ELEMS (N_ROWS * DIM)        // 8388608
#define MARGIN 0.125f
#define RESCAN_CHUNK 1024
#define RESCAN_NCHUNK (K_CODES / RESCAN_CHUNK)  // 8
#define RESCAN_ROWS 8
#define NT (DIM / BK)                   // 8 K-steps

typedef _Float16 f16;
typedef _Float16 f16x8 __attribute__((ext_vector_type(8)));
typedef float f32x4 __attribute__((ext_vector_type(4)));

// monotone float->uint map: min on packed == (min dist, then min idx)
__device__ __forceinline__ unsigned long long pack_di(float d, int i) {
  unsigned u = __float_as_uint(d);
  u = (u & 0x80000000u) ? ~u : (u | 0x80000000u);
  return ((unsigned long long)u << 32) | (unsigned)i;
}

// ---------------- kernel 0: fp32 -> fp16 cast (x) ----------------
__global__ __launch_bounds__(256) void vq_split_kernel(const float* __restrict__ src,
                                                       f16* __restrict__ x16) {
  int i = (blockIdx.x * 256 + threadIdx.x) * 8;
  float4 v0 = *(const float4*)(src + i);
  float4 v1 = *(const float4*)(src + i + 4);
  float f[8] = {v0.x, v0.y, v0.z, v0.w, v1.x, v1.y, v1.z, v1.w};
  f16x8 h;
  #pragma unroll
  for (int j = 0; j < 8; ++j) h[j] = (f16)f[j];   // RNE, rel err <= 2^-11
  *(f16x8*)(x16 + i) = h;
}

// ---------------- kernel 1: emb fp16 cast + exact fp32 norms + counter zero ----------------
// one wave per code row: 64 lanes x 8 elems = 512
__global__ __launch_bounds__(256) void vq_split_enorm_kernel(
    const float* __restrict__ emb, f16* __restrict__ e16,
    float* __restrict__ enorm, int* __restrict__ counter) {
  int gid  = blockIdx.x * 256 + threadIdx.x;
  if (gid == 0) *counter = 0;
  int code = gid >> 6;
  int lane = gid & 63;
  size_t off = (size_t)code * DIM + lane * 8;
  float4 v0 = *(const float4*)(emb + off);
  float4 v1 = *(const float4*)(emb + off + 4);
  float f[8] = {v0.x, v0.y, v0.z, v0.w, v1.x, v1.y, v1.z, v1.w};
  f16x8 h;
  float s = 0.0f;
  #pragma unroll
  for (int j = 0; j < 8; ++j) {
    h[j] = (f16)f[j];
    s = fmaf(f[j], f[j], s);
  }
  *(f16x8*)(e16 + off) = h;
  #pragma unroll
  for (int o = 32; o > 0; o >>= 1) s += __shfl_down(s, o);
  if (lane == 0) enorm[code] = s;
}

// ---------------- async global->LDS 16B helper ----------------
__device__ __forceinline__ void gl2lds16(const f16* g, f16* l) {
  __builtin_amdgcn_global_load_lds((const __attribute__((address_space(1))) unsigned int*)g,
                                   (__attribute__((address_space(3))) unsigned int*)l,
                                   16, 0, 0);
}

__device__ __forceinline__ void top2_merge(float& d1, int& i1, float& d2,
                                           float od1, int oi1, float od2) {
  if (od1 < d1 || (od1 == d1 && oi1 < i1)) {
    d2 = fminf(d1, od2);
    d1 = od1; i1 = oi1;
  } else {
    d2 = fminf(d2, od1);
  }
}

// ---------------- kernel 2: single-term fp16 MFMA GEMM + top-2 argmin ----------------
// sim = x16.e16 (fp16 in, exact fp32 accumulate); dist = ||e||^2 - 2 sim.
// Input rounding error tail << MARGIN/2; rows with gap < MARGIN get the exact
// fp32 rescan, so argmin is exact.
//
// LDS tiles [128][BK=64] fp16 = 128B rows = 8 x 16B chunks. XOR swizzle:
// chunk c of row r lives at slot c ^ (r&7). gl2lds writes linearly
// (base + lane*16), so the swizzle is realized on the GLOBAL SOURCE side
// (lane l fetches chunk (l&7)^(l>>3) of row base+(l>>3)); fragment reads
// apply the same XOR. Spreads the 16 same-k lanes across all 8 bank groups.
// Single-buffered 2-barrier structure (round-0 proven; dbuf regressed via
// occupancy loss - round-1 post-mortem / m99-m100).
__global__ __launch_bounds__(256, 2) void vq_argmin_mfma_kernel(
    const f16* __restrict__ x16, const f16* __restrict__ e16,
    const float* __restrict__ enorm,
    float* __restrict__ cand_d1, int* __restrict__ cand_i1, float* __restrict__ cand_d2) {
  __shared__ __align__(16) f16 Ax[TM * BK];   // 16 KB
  __shared__ __align__(16) f16 Be[TN * BK];   // 16 KB
  __shared__ float red_d1[2][TM];
  __shared__ int   red_i1[2][TM];
  __shared__ float red_d2[2][TM];

  const int tid  = threadIdx.x;
  const int wave = tid >> 6;
  const int lane = tid & 63;
  const int bm = blockIdx.x, bn = blockIdx.y;
  const int wr = (wave >> 1) * 64;   // wave's row offset in tile (compute role)
  const int wc = (wave & 1) * 64;    // wave's col offset in tile

  // staging role: waves 0,1 -> Ax halves; waves 2,3 -> Be halves.
  // 8 issues/wave, each issue = 8 rows x 8 swizzled 16B chunks.
  const f16* gsrc0;
  f16* ldst;
  {
    const int srow = lane >> 3;                         // 0..7
    const int scg  = ((lane & 7) ^ (lane >> 3)) * 8;    // swizzled global chunk * 8 elems
    const int rowoff = (wave & 1) * 64;
    if (wave < 2) { gsrc0 = x16 + (size_t)(bm * TM + rowoff + srow) * DIM + scg; ldst = Ax + rowoff * BK; }
    else          { gsrc0 = e16 + (size_t)(bn * TN + rowoff + srow) * DIM + scg; ldst = Be + rowoff * BK; }
  }

  f32x4 acc[4][4];
  #pragma unroll
  for (int i = 0; i < 4; ++i)
    #pragma unroll
    for (int j = 0; j < 4; ++j)
      acc[i][j] = (f32x4){0.f, 0.f, 0.f, 0.f};

  const int fr = lane & 15;   // fragment row/col within 16
  const int fq = lane >> 4;   // k-quad

  for (int t = 0; t < NT; ++t) {
    __syncthreads();   // previous iteration's LDS reads complete
    #pragma unroll
    for (int i = 0; i < 8; ++i)
      gl2lds16(gsrc0 + (size_t)(8 * i) * DIM + t * BK, ldst + (8 * i) * BK);
    __syncthreads();   // loads drained (vmcnt(0) before barrier)

    #pragma unroll
    for (int ks = 0; ks < 2; ++ks) {   // two K=32 slices of the BK=64 tile
      f16x8 a[4], b[4];
      #pragma unroll
      for (int f = 0; f < 4; ++f) {
        const int ra = wr + f * 16 + fr;
        const int rb = wc + f * 16 + fr;
        a[f] = *(const f16x8*)&Ax[ra * BK + ((ks * 4 + fq) ^ (ra & 7)) * 8];
        b[f] = *(const f16x8*)&Be[rb * BK + ((ks * 4 + fq) ^ (rb & 7)) * 8];
      }
      #pragma unroll
      for (int mf = 0; mf < 4; ++mf)
        #pragma unroll
        for (int nf = 0; nf < 4; ++nf)
          acc[mf][nf] = __builtin_amdgcn_mfma_f32_16x16x32_f16(a[mf], b[nf], acc[mf][nf], 0, 0, 0);
    }
  }

  // ---- epilogue: distances + per-row top-2 over this block's 128 cols ----
  float en[4];
  #pragma unroll
  for (int nf = 0; nf < 4; ++nf)
    en[nf] = enorm[bn * TN + wc + nf * 16 + fr];

  #pragma unroll
  for (int mf = 0; mf < 4; ++mf) {
    #pragma unroll
    for (int reg = 0; reg < 4; ++reg) {
      float d1 = 3.4e38f, d2 = 3.4e38f;
      int i1 = 0;
      #pragma unroll
      for (int nf = 0; nf < 4; ++nf) {   // ascending col keeps lowest idx on ties
        float d = en[nf] - 2.0f * acc[mf][nf][reg];
        int ci = bn * TN + wc + nf * 16 + fr;
        if (d < d1) { d2 = d1; d1 = d; i1 = ci; }
        else if (d < d2) { d2 = d; }
      }
      // butterfly over the 16 lanes (same fq) holding this row's 64 cols
      #pragma unroll
      for (int m = 1; m <= 8; m <<= 1) {
        float od1 = __shfl_xor(d1, m, 16);
        int   oi1 = __shfl_xor(i1, m, 16);
        float od2 = __shfl_xor(d2, m, 16);
        top2_merge(d1, i1, d2, od1, oi1, od2);
      }
      if (fr == 0) {
        int row = wr + mf * 16 + fq * 4 + reg;
        red_d1[wave & 1][row] = d1;
        red_i1[wave & 1][row] = i1;
        red_d2[wave & 1][row] = d2;
      }
    }
  }
  __syncthreads();
  if (tid < TM) {
    float d1 = red_d1[0][tid]; int i1 = red_i1[0][tid]; float d2 = red_d2[0][tid];
    top2_merge(d1, i1, d2, red_d1[1][tid], red_i1[1][tid], red_d2[1][tid]);
    size_t o = (size_t)bn * N_ROWS + (size_t)bm * TM + tid;
    cand_d1[o] = d1; cand_i1[o] = i1; cand_d2[o] = d2;
  }
}

// ---------------- kernel 3: merge 64 groups -> idx, flag + compacted work list ----------------
__global__ __launch_bounds__(256) void vq_merge2_kernel(
    const float* __restrict__ cd1, const int* __restrict__ ci1, const float* __restrict__ cd2,
    int* __restrict__ idx, int* __restrict__ flag,
    int* __restrict__ counter, int* __restrict__ flagged,
    unsigned long long* __restrict__ packed,
    float* __restrict__ loss_slot) {
  int r = blockIdx.x * 256 + threadIdx.x;
  if (r == 0) *loss_slot = 0.0f;
  float d1 = 3.4e38f, d2 = 3.4e38f;
  int i1 = 0;
  for (int g = 0; g < NG; ++g) {   // ascending g = ascending col blocks
    size_t o = (size_t)g * N_ROWS + r;
    top2_merge(d1, i1, d2, cd1[o], ci1[o], cd2[o]);
  }
  idx[r] = i1;
  int f = (d2 - d1 < MARGIN) ? 1 : 0;
  flag[r] = f;
  if (f) {
    packed[r] = 0xFFFFFFFFFFFFFFFFULL;
    int slot = atomicAdd(counter, 1);
    flagged[slot] = r;
  }
}

// ---------------- kernel 4: exact fp32 rescan, 8 rows per codebook pass ----------------
// Per-code arithmetic (s0..s3 lanes, (s0+s1)+(s2+s3)) kept bit-identical to the
// verified round-0 rescan; only the batching over rows changed (margin 0.125
// flags ~2-4% of rows, so the codebook read is amortized over 8 rows).
__global__ __launch_bounds__(256) void vq_rescan_kernel(
    const float* __restrict__ x, const float* __restrict__ emb,
    const float* __restrict__ enorm,
    const int* __restrict__ counter, const int* __restrict__ flagged,
    unsigned long long* __restrict__ packed) {
  __shared__ float4 xs[RESCAN_ROWS][DIM / 4];          // 16 KB
  __shared__ unsigned long long wmin[4][RESCAN_ROWS];  // 256 B
  const int t  = threadIdx.x;
  const int wv = t >> 6, ln = t & 63;
  const int nflag   = counter[0];
  const int ngroups = (nflag + RESCAN_ROWS - 1) / RESCAN_ROWS;
  const int nitems  = ngroups * RESCAN_NCHUNK;
  for (int item = blockIdx.x; item < nitems; item += gridDim.x) {
    const int g  = item / RESCAN_NCHUNK;
    const int c0 = (item % RESCAN_NCHUNK) * RESCAN_CHUNK;
    __syncthreads();   // protect xs from previous iteration's readers
    #pragma unroll
    for (int u = 0; u < 4; ++u) {
      int i4 = u * 256 + t;                 // 0..1023 float4 slots
      int j = i4 >> 7, k = i4 & 127;
      int rj = g * RESCAN_ROWS + j;
      if (rj < nflag) xs[j][k] = ((const float4*)(x + (size_t)flagged[rj] * DIM))[k];
    }
    __syncthreads();
    unsigned long long best[RESCAN_ROWS];
    #pragma unroll
    for (int j = 0; j < RESCAN_ROWS; ++j) best[j] = ~0ULL;
    #pragma unroll
    for (int cc = 0; cc < RESCAN_CHUNK / 256; ++cc) {
      const int c = c0 + cc * 256 + t;
      const float4* e4 = (const float4*)(emb + (size_t)c * DIM);
      float s0[RESCAN_ROWS], s1[RESCAN_ROWS], s2[RESCAN_ROWS], s3[RESCAN_ROWS];
      #pragma unroll
      for (int j = 0; j < RESCAN_ROWS; ++j) { s0[j] = s1[j] = s2[j] = s3[j] = 0.f; }
      for (int k = 0; k < DIM / 4; ++k) {
        float4 ev = e4[k];
        #pragma unroll
        for (int j = 0; j < RESCAN_ROWS; ++j) {
          float4 xv = xs[j][k];              // broadcast read, conflict-free
          s0[j] = fmaf(xv.x, ev.x, s0[j]);
          s1[j] = fmaf(xv.y, ev.y, s1[j]);
          s2[j] = fmaf(xv.z, ev.z, s2[j]);
          s3[j] = fmaf(xv.w, ev.w, s3[j]);
        }
      }
      const float en = enorm[c];
      #pragma unroll
      for (int j = 0; j < RESCAN_ROWS; ++j) {
        float d = en - 2.0f * ((s0[j] + s1[j]) + (s2[j] + s3[j]));
        unsigned long long p = pack_di(d, c);
        if (p < best[j]) best[j] = p;
      }
    }
    // wave reduce (packed u64 min == lexicographic (dist, idx) min)
    #pragma unroll
    for (int j = 0; j < RESCAN_ROWS; ++j) {
      #pragma unroll
      for (int off = 32; off > 0; off >>= 1) {
        unsigned long long o = __shfl_down(best[j], off);
        if (o < best[j]) best[j] = o;
      }
    }
    if (ln == 0) {
      #pragma unroll
      for (int j = 0; j < RESCAN_ROWS; ++j) wmin[wv][j] = best[j];
    }
    __syncthreads();
    if (t < RESCAN_ROWS) {
      int rj = g * RESCAN_ROWS + t;
      if (rj < nflag) {
        unsigned long long m = wmin[0][t];
        if (wmin[1][t] < m) m = wmin[1][t];
        if (wmin[2][t] < m) m = wmin[2][t];
        if (wmin[3][t] < m) m = wmin[3][t];
        atomicMin(&packed[flagged[rj]], m);
      }
    }
  }
}

// ---------------- kernel 5: gather + outputs + loss ----------------
__global__ __launch_bounds__(256) void vq_gather_kernel(
    const float* __restrict__ x, const float* __restrict__ emb,
    const int* __restrict__ idx, const int* __restrict__ flag,
    const unsigned long long* __restrict__ packed,
    float* __restrict__ out, float* __restrict__ quant,
    float* __restrict__ loss_slot) {
  __shared__ float wsum[4];
  const int wave = threadIdx.x >> 6;
  const int lane = threadIdx.x & 63;
  const int row  = blockIdx.x * 4 + wave;
  const int code = flag[row] ? (int)(packed[row] & 0xFFFFFFFFu) : idx[row];
  const float4* xp = (const float4*)(x   + (size_t)row  * DIM + lane * 8);
  const float4* ep = (const float4*)(emb + (size_t)code * DIM + lane * 8);
  float s = 0.0f;
  #pragma unroll
  for (int t = 0; t < 2; ++t) {
    float4 xv = xp[t];
    float4 ev = ep[t];
    float dx = ev.x - xv.x, dy = ev.y - xv.y, dz = ev.z - xv.z, dw = ev.w - xv.w;
    s += dx * dx + dy * dy + dz * dz + dw * dw;
    ((float4*)(out   + (size_t)row * DIM + lane * 8))[t] = ev;  // out == quantized (straight-through)
    ((float4*)(quant + (size_t)row * DIM + lane * 8))[t] = ev;
  }
  #pragma unroll
  for (int off = 32; off > 0; off >>= 1) s += __shfl_down(s, off);
  if (lane == 0) wsum[wave] = s;
  __syncthreads();
  if (threadIdx.x == 0) {
    float tot = wsum[0] + wsum[1] + wsum[2] + wsum[3];
    atomicAdd(loss_slot, tot * (1.25f / (float)OUT_ELEMS));
  }
}

extern "C" void kernel_launch(void* const* d_in, const int* in_sizes, int n_in,
                              void* d_out, int out_size, void* d_ws, size_t ws_size,
                              hipStream_t stream) {
  const float* x   = (const float*)d_in[0];   // [16384, 512]
  const float* emb = (const float*)d_in[1];   // [8192, 512]
  float* out   = (float*)d_out;
  float* quant = out + OUT_ELEMS;
  float* loss  = out + 2 * OUT_ELEMS;

  char* ws = (char*)d_ws;
  f16*   x16    = (f16*)(ws);                           // 16.78 MB
  f16*   e16    = (f16*)(ws + 16777216);                //  8.39 MB
  float* enorm  = (float*)(ws + 25165824);              // 32 KB
  float* cd1    = (float*)(ws + 25198592);              // 4 MB
  int*   ci1    = (int*)  (ws + 29392896);              // 4 MB
  float* cd2    = (float*)(ws + 33587200);              // 4 MB
  int*   idx    = (int*)  (ws + 37781504);              // 64 KB
  int*   flag   = (int*)  (ws + 37847040);              // 64 KB
  int*   counter= (int*)  (ws + 37912576);              // 4 B (+pad)
  int*   flagged= (int*)  (ws + 37912832);              // 64 KB
  unsigned long long* packed = (unsigned long long*)(ws + 37978368); // 128 KB

  vq_split_kernel<<<OUT_ELEMS / (8 * 256), 256, 0, stream>>>(x, x16);
  vq_split_enorm_kernel<<<K_CODES * 64 / 256, 256, 0, stream>>>(emb, e16, enorm, counter);
  vq_argmin_mfma_kernel<<<dim3(N_ROWS / TM, K_CODES / TN), 256, 0, stream>>>(
      x16, e16, enorm, cd1, ci1, cd2);
  vq_merge2_kernel<<<N_ROWS / 256, 256, 0, stream>>>(
      cd1, ci1, cd2, idx, flag, counter, flagged, packed, loss);
  vq_rescan_kernel<<<2048, 256, 0, stream>>>(x, emb, enorm, counter, flagged, packed);
  vq_gather_kernel<<<N_ROWS / 4, 256, 0, stream>>>(x, emb, idx, flag, packed, out, quant, loss);
}

// Round 3
// 533.767 us; speedup vs baseline: 1.2873x; 1.0934x over previous
//
#include <hip/hip_runtime.h>

#define DIM 512
#define N_ROWS 16384
#define K_CODES 8192
#define BK 32
#define TM 128
#define TN 128
#define NG (K_CODES / TN)               // 64 code groups
#define OUT_ELEMS (N_ROWS * DIM)        // 8388608
#define MARGIN 0.125f
#define RESCAN_CHUNK 1024
#define RESCAN_NCHUNK (K_CODES / RESCAN_CHUNK)  // 8
#define RESCAN_ROWS 8
#define NT (DIM / BK)                   // 16 K-steps

typedef _Float16 f16;
typedef _Float16 f16x8 __attribute__((ext_vector_type(8)));
typedef float f32x4 __attribute__((ext_vector_type(4)));

// monotone float->uint map: min on packed == (min dist, then min idx)
__device__ __forceinline__ unsigned long long pack_di(float d, int i) {
  unsigned u = __float_as_uint(d);
  u = (u & 0x80000000u) ? ~u : (u | 0x80000000u);
  return ((unsigned long long)u << 32) | (unsigned)i;
}

// ---------------- kernel 0: fp32 -> fp16 cast (x) ----------------
__global__ __launch_bounds__(256) void vq_split_kernel(const float* __restrict__ src,
                                                       f16* __restrict__ x16) {
  int i = (blockIdx.x * 256 + threadIdx.x) * 8;
  float4 v0 = *(const float4*)(src + i);
  float4 v1 = *(const float4*)(src + i + 4);
  float f[8] = {v0.x, v0.y, v0.z, v0.w, v1.x, v1.y, v1.z, v1.w};
  f16x8 h;
  #pragma unroll
  for (int j = 0; j < 8; ++j) h[j] = (f16)f[j];   // RNE, rel err <= 2^-11
  *(f16x8*)(x16 + i) = h;
}

// ---------------- kernel 1: emb fp16 cast + exact fp32 norms + counter zero ----------------
// one wave per code row: 64 lanes x 8 elems = 512
__global__ __launch_bounds__(256) void vq_split_enorm_kernel(
    const float* __restrict__ emb, f16* __restrict__ e16,
    float* __restrict__ enorm, int* __restrict__ counter) {
  int gid  = blockIdx.x * 256 + threadIdx.x;
  if (gid == 0) *counter = 0;
  int code = gid >> 6;
  int lane = gid & 63;
  size_t off = (size_t)code * DIM + lane * 8;
  float4 v0 = *(const float4*)(emb + off);
  float4 v1 = *(const float4*)(emb + off + 4);
  float f[8] = {v0.x, v0.y, v0.z, v0.w, v1.x, v1.y, v1.z, v1.w};
  f16x8 h;
  float s = 0.0f;
  #pragma unroll
  for (int j = 0; j < 8; ++j) {
    h[j] = (f16)f[j];
    s = fmaf(f[j], f[j], s);
  }
  *(f16x8*)(e16 + off) = h;
  #pragma unroll
  for (int o = 32; o > 0; o >>= 1) s += __shfl_down(s, o);
  if (lane == 0) enorm[code] = s;
}

// ---------------- async global->LDS 16B helper ----------------
__device__ __forceinline__ void gl2lds16(const f16* g, f16* l) {
  __builtin_amdgcn_global_load_lds((const __attribute__((address_space(1))) unsigned int*)g,
                                   (__attribute__((address_space(3))) unsigned int*)l,
                                   16, 0, 0);
}

__device__ __forceinline__ void top2_merge(float& d1, int& i1, float& d2,
                                           float od1, int oi1, float od2) {
  if (od1 < d1 || (od1 == d1 && oi1 < i1)) {
    d2 = fminf(d1, od2);
    d1 = od1; i1 = oi1;
  } else {
    d2 = fminf(d2, od1);
  }
}

// ---------------- kernel 2: single-term fp16 MFMA GEMM + top-2 argmin ----------------
// sim = x16.e16 (fp16 in, exact fp32 accumulate); dist = ||e||^2 - 2 sim.
// Rows with top-2 gap < MARGIN get the exact fp32 rescan, so argmin is exact.
//
// Structure (round-3): BK=32 DOUBLE-buffered with stage-ahead, ONE barrier per
// K-step (T3-minimum). LDS footprint equals the round-2 single-buffer kernel
// (~35.5 KB -> ~4 blocks/CU), so we get round-1's pipelining at round-2's
// occupancy. Each step: issue next tile's global_load_lds into buf^1, then
// ds_read + 16 MFMA on buf, then __syncthreads (its vmcnt(0) drains loads that
// have had the whole compute phase to complete).
//
// LDS tiles [128][BK=32] f16 = 64B rows = 4 x 16B chunks. XOR swizzle
// (round-0 proven, conflict-free): chunk fq of row r lives at slot
// fq ^ ((r>>1)&3). gl2lds writes linearly, so the swizzle is realized on the
// GLOBAL SOURCE side: lane l fetches chunk (l&3)^((l>>3)&3) of row (l>>2).
__global__ __launch_bounds__(256, 4) void vq_argmin_mfma_kernel(
    const f16* __restrict__ x16, const f16* __restrict__ e16,
    const float* __restrict__ enorm,
    float* __restrict__ cand_d1, int* __restrict__ cand_i1, float* __restrict__ cand_d2) {
  __shared__ __align__(16) f16 Ax[2][TM * BK];   // 8 KB per buffer
  __shared__ __align__(16) f16 Be[2][TN * BK];   // 8 KB per buffer
  __shared__ float red_d1[2][TM];
  __shared__ int   red_i1[2][TM];
  __shared__ float red_d2[2][TM];

  const int tid  = threadIdx.x;
  const int wave = tid >> 6;
  const int lane = tid & 63;
  const int bm = blockIdx.x, bn = blockIdx.y;
  const int wr = (wave >> 1) * 64;   // wave's row offset in tile (compute role)
  const int wc = (wave & 1) * 64;    // wave's col offset in tile

  // staging role: waves 0,1 -> Ax halves; waves 2,3 -> Be halves.
  // 4 issues/wave/step, each issue = 16 rows x 4 swizzled 16B chunks.
  const f16* gsrc0;
  int ldoff;   // element offset of this wave's half within a tile buffer
  {
    const int srow = lane >> 2;                         // 0..15
    const int scg  = ((lane & 3) ^ ((lane >> 3) & 3)) * 8;   // swizzled global chunk * 8 elems
    const int rowoff = (wave & 1) * 64;
    if (wave < 2) { gsrc0 = x16 + (size_t)(bm * TM + rowoff + srow) * DIM + scg; }
    else          { gsrc0 = e16 + (size_t)(bn * TN + rowoff + srow) * DIM + scg; }
    ldoff = rowoff * BK;
  }
  f16* dstA0 = (wave < 2) ? &Ax[0][ldoff] : &Be[0][ldoff];
  f16* dstA1 = (wave < 2) ? &Ax[1][ldoff] : &Be[1][ldoff];

  f32x4 acc[4][4];
  #pragma unroll
  for (int i = 0; i < 4; ++i)
    #pragma unroll
    for (int j = 0; j < 4; ++j)
      acc[i][j] = (f32x4){0.f, 0.f, 0.f, 0.f};

  const int fr = lane & 15;   // fragment row/col within 16
  const int fq = lane >> 4;   // k-quad
  const int sw8 = (fq ^ ((fr >> 1) & 3)) * 8;   // read-side swizzled chunk * 8 elems

  // prologue: stage K-step 0 into buffer 0
  #pragma unroll
  for (int i = 0; i < 4; ++i)
    gl2lds16(gsrc0 + (size_t)(16 * i) * DIM, dstA0 + (16 * i) * BK);
  __syncthreads();   // vmcnt(0) drain: step-0 tiles resident

  #pragma unroll 2
  for (int s = 0; s < NT; ++s) {
    const int cur = s & 1;
    // stage-ahead: next K-step into the other buffer BEFORE compute.
    // Safe: buf^1's readers finished before the barrier ending step s-1.
    if (s + 1 < NT) {
      f16* nb = cur ? dstA0 : dstA1;
      const int k1 = (s + 1) * BK;
      #pragma unroll
      for (int i = 0; i < 4; ++i)
        gl2lds16(gsrc0 + (size_t)(16 * i) * DIM + k1, nb + (16 * i) * BK);
    }

    const f16* A = cur ? &Ax[1][0] : &Ax[0][0];
    const f16* B = cur ? &Be[1][0] : &Be[0][0];
    f16x8 a[4], b[4];
    #pragma unroll
    for (int f = 0; f < 4; ++f) {
      a[f] = *(const f16x8*)&A[(wr + f * 16 + fr) * BK + sw8];
      b[f] = *(const f16x8*)&B[(wc + f * 16 + fr) * BK + sw8];
    }
    #pragma unroll
    for (int mf = 0; mf < 4; ++mf)
      #pragma unroll
      for (int nf = 0; nf < 4; ++nf)
        acc[mf][nf] = __builtin_amdgcn_mfma_f32_16x16x32_f16(a[mf], b[nf], acc[mf][nf], 0, 0, 0);

    __syncthreads();   // drains stage-ahead loads (covered by MFMA) + joins waves
  }

  // ---- epilogue: distances + per-row top-2 over this block's 128 cols ----
  float en[4];
  #pragma unroll
  for (int nf = 0; nf < 4; ++nf)
    en[nf] = enorm[bn * TN + wc + nf * 16 + fr];

  #pragma unroll
  for (int mf = 0; mf < 4; ++mf) {
    #pragma unroll
    for (int reg = 0; reg < 4; ++reg) {
      float d1 = 3.4e38f, d2 = 3.4e38f;
      int i1 = 0;
      #pragma unroll
      for (int nf = 0; nf < 4; ++nf) {   // ascending col keeps lowest idx on ties
        float d = en[nf] - 2.0f * acc[mf][nf][reg];
        int ci = bn * TN + wc + nf * 16 + fr;
        if (d < d1) { d2 = d1; d1 = d; i1 = ci; }
        else if (d < d2) { d2 = d; }
      }
      // butterfly over the 16 lanes (same fq) holding this row's 64 cols
      #pragma unroll
      for (int m = 1; m <= 8; m <<= 1) {
        float od1 = __shfl_xor(d1, m, 16);
        int   oi1 = __shfl_xor(i1, m, 16);
        float od2 = __shfl_xor(d2, m, 16);
        top2_merge(d1, i1, d2, od1, oi1, od2);
      }
      if (fr == 0) {
        int row = wr + mf * 16 + fq * 4 + reg;
        red_d1[wave & 1][row] = d1;
        red_i1[wave & 1][row] = i1;
        red_d2[wave & 1][row] = d2;
      }
    }
  }
  __syncthreads();
  if (tid < TM) {
    float d1 = red_d1[0][tid]; int i1 = red_i1[0][tid]; float d2 = red_d2[0][tid];
    top2_merge(d1, i1, d2, red_d1[1][tid], red_i1[1][tid], red_d2[1][tid]);
    size_t o = (size_t)bn * N_ROWS + (size_t)bm * TM + tid;
    cand_d1[o] = d1; cand_i1[o] = i1; cand_d2[o] = d2;
  }
}

// ---------------- kernel 3: merge 64 groups -> idx, flag + compacted work list ----------------
__global__ __launch_bounds__(256) void vq_merge2_kernel(
    const float* __restrict__ cd1, const int* __restrict__ ci1, const float* __restrict__ cd2,
    int* __restrict__ idx, int* __restrict__ flag,
    int* __restrict__ counter, int* __restrict__ flagged,
    unsigned long long* __restrict__ packed,
    float* __restrict__ loss_slot) {
  int r = blockIdx.x * 256 + threadIdx.x;
  if (r == 0) *loss_slot = 0.0f;
  float d1 = 3.4e38f, d2 = 3.4e38f;
  int i1 = 0;
  for (int g = 0; g < NG; ++g) {   // ascending g = ascending col blocks
    size_t o = (size_t)g * N_ROWS + r;
    top2_merge(d1, i1, d2, cd1[o], ci1[o], cd2[o]);
  }
  idx[r] = i1;
  int f = (d2 - d1 < MARGIN) ? 1 : 0;
  flag[r] = f;
  if (f) {
    packed[r] = 0xFFFFFFFFFFFFFFFFULL;
    int slot = atomicAdd(counter, 1);
    flagged[slot] = r;
  }
}

// ---------------- kernel 4: exact fp32 rescan, 8 rows per codebook pass ----------------
// Per-code arithmetic (s0..s3 lanes, (s0+s1)+(s2+s3)) kept bit-identical to the
// verified round-0 rescan; only the batching over rows changed.
__global__ __launch_bounds__(256) void vq_rescan_kernel(
    const float* __restrict__ x, const float* __restrict__ emb,
    const float* __restrict__ enorm,
    const int* __restrict__ counter, const int* __restrict__ flagged,
    unsigned long long* __restrict__ packed) {
  __shared__ float4 xs[RESCAN_ROWS][DIM / 4];          // 16 KB
  __shared__ unsigned long long wmin[4][RESCAN_ROWS];  // 256 B
  const int t  = threadIdx.x;
  const int wv = t >> 6, ln = t & 63;
  const int nflag   = counter[0];
  const int ngroups = (nflag + RESCAN_ROWS - 1) / RESCAN_ROWS;
  const int nitems  = ngroups * RESCAN_NCHUNK;
  for (int item = blockIdx.x; item < nitems; item += gridDim.x) {
    const int g  = item / RESCAN_NCHUNK;
    const int c0 = (item % RESCAN_NCHUNK) * RESCAN_CHUNK;
    __syncthreads();   // protect xs from previous iteration's readers
    #pragma unroll
    for (int u = 0; u < 4; ++u) {
      int i4 = u * 256 + t;                 // 0..1023 float4 slots
      int j = i4 >> 7, k = i4 & 127;
      int rj = g * RESCAN_ROWS + j;
      if (rj < nflag) xs[j][k] = ((const float4*)(x + (size_t)flagged[rj] * DIM))[k];
    }
    __syncthreads();
    unsigned long long best[RESCAN_ROWS];
    #pragma unroll
    for (int j = 0; j < RESCAN_ROWS; ++j) best[j] = ~0ULL;
    #pragma unroll
    for (int cc = 0; cc < RESCAN_CHUNK / 256; ++cc) {
      const int c = c0 + cc * 256 + t;
      const float4* e4 = (const float4*)(emb + (size_t)c * DIM);
      float s0[RESCAN_ROWS], s1[RESCAN_ROWS], s2[RESCAN_ROWS], s3[RESCAN_ROWS];
      #pragma unroll
      for (int j = 0; j < RESCAN_ROWS; ++j) { s0[j] = s1[j] = s2[j] = s3[j] = 0.f; }
      for (int k = 0; k < DIM / 4; ++k) {
        float4 ev = e4[k];
        #pragma unroll
        for (int j = 0; j < RESCAN_ROWS; ++j) {
          float4 xv = xs[j][k];              // broadcast read, conflict-free
          s0[j] = fmaf(xv.x, ev.x, s0[j]);
          s1[j] = fmaf(xv.y, ev.y, s1[j]);
          s2[j] = fmaf(xv.z, ev.z, s2[j]);
          s3[j] = fmaf(xv.w, ev.w, s3[j]);
        }
      }
      const float en = enorm[c];
      #pragma unroll
      for (int j = 0; j < RESCAN_ROWS; ++j) {
        float d = en - 2.0f * ((s0[j] + s1[j]) + (s2[j] + s3[j]));
        unsigned long long p = pack_di(d, c);
        if (p < best[j]) best[j] = p;
      }
    }
    // wave reduce (packed u64 min == lexicographic (dist, idx) min)
    #pragma unroll
    for (int j = 0; j < RESCAN_ROWS; ++j) {
      #pragma unroll
      for (int off = 32; off > 0; off >>= 1) {
        unsigned long long o = __shfl_down(best[j], off);
        if (o < best[j]) best[j] = o;
      }
    }
    if (ln == 0) {
      #pragma unroll
      for (int j = 0; j < RESCAN_ROWS; ++j) wmin[wv][j] = best[j];
    }
    __syncthreads();
    if (t < RESCAN_ROWS) {
      int rj = g * RESCAN_ROWS + t;
      if (rj < nflag) {
        unsigned long long m = wmin[0][t];
        if (wmin[1][t] < m) m = wmin[1][t];
        if (wmin[2][t] < m) m = wmin[2][t];
        if (wmin[3][t] < m) m = wmin[3][t];
        atomicMin(&packed[flagged[rj]], m);
      }
    }
  }
}

// ---------------- kernel 5: gather + outputs + loss ----------------
__global__ __launch_bounds__(256) void vq_gather_kernel(
    const float* __restrict__ x, const float* __restrict__ emb,
    const int* __restrict__ idx, const int* __restrict__ flag,
    const unsigned long long* __restrict__ packed,
    float* __restrict__ out, float* __restrict__ quant,
    float* __restrict__ loss_slot) {
  __shared__ float wsum[4];
  const int wave = threadIdx.x >> 6;
  const int lane = threadIdx.x & 63;
  const int row  = blockIdx.x * 4 + wave;
  const int code = flag[row] ? (int)(packed[row] & 0xFFFFFFFFu) : idx[row];
  const float4* xp = (const float4*)(x   + (size_t)row  * DIM + lane * 8);
  const float4* ep = (const float4*)(emb + (size_t)code * DIM + lane * 8);
  float s = 0.0f;
  #pragma unroll
  for (int t = 0; t < 2; ++t) {
    float4 xv = xp[t];
    float4 ev = ep[t];
    float dx = ev.x - xv.x, dy = ev.y - xv.y, dz = ev.z - xv.z, dw = ev.w - xv.w;
    s += dx * dx + dy * dy + dz * dz + dw * dw;
    ((float4*)(out   + (size_t)row * DIM + lane * 8))[t] = ev;  // out == quantized (straight-through)
    ((float4*)(quant + (size_t)row * DIM + lane * 8))[t] = ev;
  }
  #pragma unroll
  for (int off = 32; off > 0; off >>= 1) s += __shfl_down(s, off);
  if (lane == 0) wsum[wave] = s;
  __syncthreads();
  if (threadIdx.x == 0) {
    float tot = wsum[0] + wsum[1] + wsum[2] + wsum[3];
    atomicAdd(loss_slot, tot * (1.25f / (float)OUT_ELEMS));
  }
}

extern "C" void kernel_launch(void* const* d_in, const int* in_sizes, int n_in,
                              void* d_out, int out_size, void* d_ws, size_t ws_size,
                              hipStream_t stream) {
  const float* x   = (const float*)d_in[0];   // [16384, 512]
  const float* emb = (const float*)d_in[1];   // [8192, 512]
  float* out   = (float*)d_out;
  float* quant = out + OUT_ELEMS;
  float* loss  = out + 2 * OUT_ELEMS;

  char* ws = (char*)d_ws;
  f16*   x16    = (f16*)(ws);                           // 16.78 MB
  f16*   e16    = (f16*)(ws + 16777216);                //  8.39 MB
  float* enorm  = (float*)(ws + 25165824);              // 32 KB
  float* cd1    = (float*)(ws + 25198592);              // 4 MB
  int*   ci1    = (int*)  (ws + 29392896);              // 4 MB
  float* cd2    = (float*)(ws + 33587200);              // 4 MB
  int*   idx    = (int*)  (ws + 37781504);              // 64 KB
  int*   flag   = (int*)  (ws + 37847040);              // 64 KB
  int*   counter= (int*)  (ws + 37912576);              // 4 B (+pad)
  int*   flagged= (int*)  (ws + 37912832);              // 64 KB
  unsigned long long* packed = (unsigned long long*)(ws + 37978368); // 128 KB

  vq_split_kernel<<<OUT_ELEMS / (8 * 256), 256, 0, stream>>>(x, x16);
  vq_split_enorm_kernel<<<K_CODES * 64 / 256, 256, 0, stream>>>(emb, e16, enorm, counter);
  vq_argmin_mfma_kernel<<<dim3(N_ROWS / TM, K_CODES / TN), 256, 0, stream>>>(
      x16, e16, enorm, cd1, ci1, cd2);
  vq_merge2_kernel<<<N_ROWS / 256, 256, 0, stream>>>(
      cd1, ci1, cd2, idx, flag, counter, flagged, packed, loss);
  vq_rescan_kernel<<<2048, 256, 0, stream>>>(x, emb, enorm, counter, flagged, packed);
  vq_gather_kernel<<<N_ROWS / 4, 256, 0, stream>>>(x, emb, idx, flag, packed, out, quant, loss);
}